// Round 1
// 228.092 us; speedup vs baseline: 1.0602x; 1.0602x over previous
//
#include <hip/hip_runtime.h>
#include <hip/hip_bf16.h>

#define TOKS   32768
#define NEXP   64
#define DDIM   1024
#define SEQ    8192
#define NBATCH 4
#define TPB    64      // tokens per block
#define STR    68      // epilogue row stride (floats)
#define CSTR   21      // candidate row stride
#define BK     128     // K-chunk per staging step
#define NCH    (DDIM / BK)   // 8
#define ASTR   136     // bf16 row stride of staged tiles (+8 pad -> dense-equivalent banks)

typedef __attribute__((ext_vector_type(8))) short short8v;  // 8 bf16 = 4 VGPRs (MFMA A/B frag)
typedef __attribute__((ext_vector_type(4))) float f32x4;    // 16x16x32 accumulator

// Split one float4 into bf16 hi (RNE) and bf16 lo = RNE(x - hi).
// hi*hi + hi*lo + lo*hi in f32-accum MFMA reproduces fp32 logits to ~1e-6 abs.
__device__ __forceinline__ void stage4(ushort* dh, ushort* dl, float4 v) {
  __hip_bfloat162 h0 = __float22bfloat162_rn(make_float2(v.x, v.y));
  __hip_bfloat162 h1 = __float22bfloat162_rn(make_float2(v.z, v.w));
  float2 f0 = __bfloat1622float2(h0);
  float2 f1 = __bfloat1622float2(h1);
  __hip_bfloat162 l0 = __float22bfloat162_rn(make_float2(v.x - f0.x, v.y - f0.y));
  __hip_bfloat162 l1 = __float22bfloat162_rn(make_float2(v.z - f1.x, v.w - f1.y));
  *(__hip_bfloat162*)(dh)     = h0;
  *(__hip_bfloat162*)(dh + 2) = h1;
  *(__hip_bfloat162*)(dl)     = l0;
  *(__hip_bfloat162*)(dl + 2) = l1;
}

// ---------------- main kernel: bf16x2 MFMA GEMM + softmax + top-9 + flagging ----------------
__global__ __launch_bounds__(256, 2) void moe_gate_main(
    const float* __restrict__ X, const float* __restrict__ W,
    float* __restrict__ out, float* __restrict__ gsum, float* __restrict__ gce,
    int* __restrict__ flag_cnt, int* __restrict__ flag_tok)
{
  // 69632 B pool: GEMM phase = 4 bf16 tiles [64][ASTR]; epilogue aliases the
  // same memory with the proven round-3 layout (47104 B).
  __shared__ __align__(16) char smem[4 * 64 * ASTR * 2];

  ushort* Ah = (ushort*)smem;            // X-tile hi  [64][ASTR]
  ushort* Al = Ah + 64 * ASTR;           // X-tile lo
  ushort* Bh = Al + 64 * ASTR;           // W-tile hi
  ushort* Bl = Bh + 64 * ASTR;           // W-tile lo

  float* xs   = (float*)smem;            // scoresT [64][STR]
  float* wsm  = (float*)(smem + 17408);  // logits  [64][STR]
  float* red  = (float*)(smem + 34816);  // [256]
  float* gmx  = (float*)(smem + 35840);  // [64]
  float* cval = (float*)(smem + 36096);  // [64*CSTR]
  int*   cidx = (int*)  (smem + 41472);  // [64*CSTR]
  int*   hist = (int*)  (smem + 46848);  // [64]

  const int tid = threadIdx.x;
  const int tok_base = blockIdx.x * TPB;
  const int bb = blockIdx.x >> 7;        // 128 blocks per batch

  const int l = tid & 63;
  const int q = tid >> 6;

  // staging map: 32 float4 cols x 8 rows per pass, 8 passes -> 64 rows x 128 f32
  const int c4 = tid & 31;
  const int r0 = tid >> 5;

  // MFMA map: wave q owns 32x32 quadrant (wm: token half, wn: expert half)
  const int wm = q >> 1, wn = q & 1;
  const int fr = l & 15;                 // row within 16-tile
  const int fk = (l >> 4) * 8;           // contiguous-8 k offset within K=32

  f32x4 accA[2][2], accB[2][2];
#pragma unroll
  for (int i = 0; i < 2; ++i)
#pragma unroll
    for (int j = 0; j < 2; ++j) {
      accA[i][j] = (f32x4)0.0f;
      accB[i][j] = (f32x4)0.0f;
    }

  float4 px[8], pw[8];
#pragma unroll
  for (int i = 0; i < 8; ++i) {
    px[i] = *(const float4*)(X + (size_t)(tok_base + r0 + 8 * i) * DDIM + 4 * c4);
    pw[i] = *(const float4*)(W + (size_t)(r0 + 8 * i) * DDIM + 4 * c4);
  }

#pragma unroll 1
  for (int kt = 0; kt < NCH; ++kt) {
    __syncthreads();                     // prev MFMA done reading LDS
#pragma unroll
    for (int i = 0; i < 8; ++i) {
      const int row = r0 + 8 * i;
      stage4(&Ah[row * ASTR + 4 * c4], &Al[row * ASTR + 4 * c4], px[i]);
      stage4(&Bh[row * ASTR + 4 * c4], &Bl[row * ASTR + 4 * c4], pw[i]);
    }
    __syncthreads();
    if (kt + 1 < NCH) {
      const int db = (kt + 1) * BK;
#pragma unroll
      for (int i = 0; i < 8; ++i) {
        px[i] = *(const float4*)(X + (size_t)(tok_base + r0 + 8 * i) * DDIM + db + 4 * c4);
        pw[i] = *(const float4*)(W + (size_t)(r0 + 8 * i) * DDIM + db + 4 * c4);
      }
    }
#pragma unroll
    for (int s = 0; s < BK / 32; ++s) {
      const int ko = s * 32 + fk;
      short8v a_h[2], a_l[2], b_h[2], b_l[2];
#pragma unroll
      for (int i = 0; i < 2; ++i) {
        const ushort* pa = Ah + (size_t)(32 * wm + 16 * i + fr) * ASTR + ko;
        a_h[i] = *(const short8v*)pa;
        a_l[i] = *(const short8v*)(pa + 64 * ASTR);
        const ushort* pb = Bh + (size_t)(32 * wn + 16 * i + fr) * ASTR + ko;
        b_h[i] = *(const short8v*)pb;
        b_l[i] = *(const short8v*)(pb + 64 * ASTR);
      }
#pragma unroll
      for (int i = 0; i < 2; ++i)
#pragma unroll
        for (int j = 0; j < 2; ++j) {
          accA[i][j] = __builtin_amdgcn_mfma_f32_16x16x32_bf16(a_h[i], b_h[j], accA[i][j], 0, 0, 0);
          accB[i][j] = __builtin_amdgcn_mfma_f32_16x16x32_bf16(a_l[i], b_h[j], accB[i][j], 0, 0, 0);
          accA[i][j] = __builtin_amdgcn_mfma_f32_16x16x32_bf16(a_h[i], b_l[j], accA[i][j], 0, 0, 0);
        }
    }
  }

  __syncthreads();                       // all MFMA reads done; smem -> epilogue layout
  // C/D layout (m89-verified): col = lane&15, row = (lane>>4)*4 + reg
#pragma unroll
  for (int i = 0; i < 2; ++i)
#pragma unroll
    for (int j = 0; j < 2; ++j) {
      f32x4 c = accA[i][j] + accB[i][j];
      const int tok = 32 * wm + 16 * i + 4 * (l >> 4);
      const int e   = 32 * wn + 16 * j + fr;
#pragma unroll
      for (int r = 0; r < 4; ++r)
        wsm[(tok + r) * STR + e] = c[r];
    }
  if (tid < 64) hist[tid] = 0;
  __syncthreads();

  // ---- epilogue (round-3 layout, unchanged) ----
  float* logits  = wsm;   // [t][STR]
  float* scoresT = xs;    // [e][STR]
  const int t = l;

  float m = -__builtin_huge_valf();
#pragma unroll
  for (int e = 0; e < 16; ++e) m = fmaxf(m, logits[t * STR + q * 16 + e]);
  red[q * 64 + t] = m;
  __syncthreads();
  float gm = fmaxf(fmaxf(red[t], red[64 + t]), fmaxf(red[128 + t], red[192 + t]));
  if (q == 0) gmx[t] = gm;
  float z = 0.0f;
#pragma unroll
  for (int e = 0; e < 16; ++e) {
    float ev = expf(logits[t * STR + q * 16 + e] - gm);
    scoresT[(q * 16 + e) * STR + t] = ev;
    z += ev;
  }
  __syncthreads();
  red[q * 64 + t] = z;
  __syncthreads();
  float Z = red[t] + red[64 + t] + red[128 + t] + red[192 + t];
  float invZ = 1.0f / Z;
#pragma unroll
  for (int e = 0; e < 16; ++e) scoresT[(q * 16 + e) * STR + t] *= invZ;
  __syncthreads();

  // aux partials: sum scores over this block's tokens, per expert
  {
    const int e = l, g = q;
    float s = 0.0f;
#pragma unroll
    for (int tt = 0; tt < 16; ++tt) s += scoresT[e * STR + g * 16 + tt];
    red[g * 64 + e] = s;
  }
  __syncthreads();
  if (tid < 64) {
    float tot = red[tid] + red[64 + tid] + red[128 + tid] + red[192 + tid];
    atomicAdd(&gsum[bb * 64 + tid], tot);
  }

  // top-9 phase 1: per half (32 experts), strict > + ascending scan == jax tie-break
  if (tid < 128) {
    const int h = tid >> 6;
    const int eb = h * 32;
#pragma unroll 1
    for (int k = 0; k < 9; ++k) {
      float mv = -1.0f; int mi = eb;
#pragma unroll 4
      for (int e = 0; e < 32; ++e) {
        float v = scoresT[(eb + e) * STR + t];
        if (v > mv) { mv = v; mi = eb + e; }
      }
      cval[t * CSTR + h * 9 + k] = mv;
      cidx[t * CSTR + h * 9 + k] = mi;
      scoresT[mi * STR + t] = -1.0f;
    }
  }
  __syncthreads();

  // merge 18 -> top-9; flag near-ties for f64 refinement
  if (tid < 64) {
    float wv[9]; int wi[8];
#pragma unroll 1
    for (int k = 0; k < 9; ++k) {
      float mv = -1.0f; int mj = 0;
#pragma unroll 3
      for (int j = 0; j < 18; ++j) {
        float v = cval[t * CSTR + j];
        if (v > mv) { mv = v; mj = j; }
      }
      wv[k] = mv;
      if (k < 8) {
        wi[k] = cidx[t * CSTR + mj];
        atomicAdd(&hist[wi[k]], 1);
      }
      cval[t * CSTR + mj] = -1.0f;
    }
    bool flag = false;
#pragma unroll
    for (int k = 0; k < 8; ++k)
      if (wv[k + 1] >= wv[k] * (1.0f - 2.0e-5f)) flag = true;
    if (flag) {
      int p = atomicAdd(flag_cnt, 1);
      flag_tok[p] = tok_base + t;
    }
    // weights from f64 exp of logits (Z cancels in renorm; eps 1e-20 negligible)
    double ed[8]; double den = 0.0;
#pragma unroll
    for (int k = 0; k < 8; ++k) {
      ed[k] = exp((double)logits[t * STR + wi[k]] - (double)gmx[t]);
      den += ed[k];
    }
    const size_t tg = (size_t)(tok_base + t);
    *(float4*)(out + tg * 8) =
        make_float4((float)wi[0], (float)wi[1], (float)wi[2], (float)wi[3]);
    *(float4*)(out + tg * 8 + 4) =
        make_float4((float)wi[4], (float)wi[5], (float)wi[6], (float)wi[7]);
    *(float4*)(out + (size_t)TOKS * 8 + tg * 8) =
        make_float4((float)(ed[0] / den), (float)(ed[1] / den),
                    (float)(ed[2] / den), (float)(ed[3] / den));
    *(float4*)(out + (size_t)TOKS * 8 + tg * 8 + 4) =
        make_float4((float)(ed[4] / den), (float)(ed[5] / den),
                    (float)(ed[6] / den), (float)(ed[7] / den));
  }
  __syncthreads();
  if (tid < 64) atomicAdd(&gce[bb * 64 + tid], (float)hist[tid]);
}

// ---------------- f64 refinement for flagged (near-tie) tokens ----------------
__global__ __launch_bounds__(256) void moe_refine(
    const float* __restrict__ X, const float* __restrict__ W,
    float* __restrict__ out, float* __restrict__ gce,
    const int* __restrict__ flag_cnt, const int* __restrict__ flag_tok)
{
  __shared__ __align__(16) float xrow[DDIM];
  __shared__ double part[4][NEXP];
  const int tid = threadIdx.x;
  const int n = *flag_cnt;
  const int e = tid & 63;
  const int c = tid >> 6;          // K-chunk of 256
#pragma unroll 1
  for (int it = blockIdx.x; it < n; it += 256) {
    const int tok = flag_tok[it];
    __syncthreads();
    *(float4*)&xrow[tid * 4] = *(const float4*)&X[(size_t)tok * DDIM + tid * 4];
    __syncthreads();
    const float* wr = W + (size_t)e * DDIM + c * 256;
    const float* xr = xrow + c * 256;
    double s0 = 0.0, s1 = 0.0, s2 = 0.0, s3 = 0.0;
#pragma unroll 4
    for (int j = 0; j < 256; j += 4) {
      s0 += (double)xr[j]     * (double)wr[j];
      s1 += (double)xr[j + 1] * (double)wr[j + 1];
      s2 += (double)xr[j + 2] * (double)wr[j + 2];
      s3 += (double)xr[j + 3] * (double)wr[j + 3];
    }
    part[c][e] = (s0 + s1) + (s2 + s3);
    __syncthreads();
    if (tid < 64) {
      double cur = (part[0][e] + part[1][e]) + (part[2][e] + part[3][e]);
      int wi[8]; double wl[8];
#pragma unroll 1
      for (int k = 0; k < 8; ++k) {
        double mv = cur; int mi = e;
#pragma unroll
        for (int off = 1; off < 64; off <<= 1) {
          double ov = __shfl_xor(mv, off);
          int    oi = __shfl_xor(mi, off);
          if (ov > mv || (ov == mv && oi < mi)) { mv = ov; mi = oi; }
        }
        wi[k] = mi; wl[k] = mv;
        if (e == mi) cur = -1.0e300;   // knock out winner in its owner lane
      }
      if (e == 0) {
        int olde[8];
#pragma unroll
        for (int k = 0; k < 8; ++k) olde[k] = (int)out[(size_t)tok * 8 + k];
        double ex[8]; double den = 0.0;
#pragma unroll
        for (int k = 0; k < 8; ++k) { ex[k] = exp(wl[k] - wl[0]); den += ex[k]; }
#pragma unroll
        for (int k = 0; k < 8; ++k) {
          out[(size_t)tok * 8 + k] = (float)wi[k];
          out[(size_t)TOKS * 8 + (size_t)tok * 8 + k] = (float)(ex[k] / den);
        }
        const int bbb = tok >> 13;
#pragma unroll 1
        for (int k = 0; k < 8; ++k) {
          bool in_new = false, in_old = false;
          for (int j = 0; j < 8; ++j) {
            if (wi[j] == olde[k]) in_new = true;
            if (olde[j] == wi[k]) in_old = true;
          }
          if (!in_new) atomicAdd(&gce[bbb * 64 + olde[k]], -1.0f);
          if (!in_old) atomicAdd(&gce[bbb * 64 + wi[k]], 1.0f);
        }
      }
    }
  }
}

// ---------------- aux loss reduction ----------------
__global__ void moe_gate_aux(const float* __restrict__ gsum,
                             const float* __restrict__ gce,
                             float* __restrict__ out)
{
  __shared__ float r[256];
  const int tid = threadIdx.x;
  r[tid] = gce[tid] * gsum[tid];
  __syncthreads();
  for (int s = 128; s > 0; s >>= 1) {
    if (tid < s) r[tid] += r[tid + s];
    __syncthreads();
  }
  if (tid == 0)
    out[(size_t)TOKS * 16] = 0.1f * r[0] / ((float)SEQ * (float)NBATCH);
}

extern "C" void kernel_launch(void* const* d_in, const int* in_sizes, int n_in,
                              void* d_out, int out_size, void* d_ws, size_t ws_size,
                              hipStream_t stream)
{
  const float* X = (const float*)d_in[0];   // [4,8192,1024] fp32
  const float* W = (const float*)d_in[1];   // [64,1024] fp32
  float* out  = (float*)d_out;              // idx[T*8] | weights[T*8] | aux
  float* gsum = (float*)d_ws;               // [4][64]
  float* gce  = gsum + NBATCH * NEXP;       // [4][64]
  int* flag_cnt = (int*)((char*)d_ws + 2048);
  int* flag_tok = (int*)((char*)d_ws + 2176);

  hipMemsetAsync(d_ws, 0, 2176, stream);
  moe_gate_main<<<TOKS / TPB, 256, 0, stream>>>(X, W, out, gsum, gce, flag_cnt, flag_tok);
  moe_refine<<<256, 256, 0, stream>>>(X, W, out, gce, flag_cnt, flag_tok);
  moe_gate_aux<<<1, 256, 0, stream>>>(gsum, gce, out);
}